// Round 1
// baseline (2764.666 us; speedup 1.0000x reference)
//
#include <hip/hip_runtime.h>
#include <cstddef>
#include <cstdint>
#include <math.h>

#define EPSF 1e-8f

// Model dims (fixed): T=64, B=128, D=300, H=300, L=20, AH=300, N2=2B=256

typedef _Float16 half8v __attribute__((ext_vector_type(8)));
typedef float f32x4v __attribute__((ext_vector_type(4)));
union U4H8 { uint4 u; half8v h; _Float16 e[8]; };

// fast device math: v_exp_f32 + v_rcp_f32 (rel err ~1e-7, fine for 3e-3 budget)
__device__ __forceinline__ float fsig(float x) {
  float e = __expf(-x);                       // overflow-safe: inf -> rcp(inf)=0
  return __builtin_amdgcn_rcpf(1.f + e);
}
__device__ __forceinline__ float ftanh(float x) {
  float e = __expf(-2.f * fabsf(x));          // in (0,1], never overflows
  float r = (1.f - e) * __builtin_amdgcn_rcpf(1.f + e);
  return copysignf(r, x);
}

// ---------------------------------------------------------------------------
// 128x128 NT GEMM (fp32), 8x8 micro, KT=16: C[m,n] = bias[n] + sum A[m,k]B[n,k]
// Input-gate GEMMs stay fp32: f16 here compounds with the f16 recurrence and
// blows the 3e-3 absmax budget (round-8 failure: 1.4e-2).
// ---------------------------------------------------------------------------
__global__ __launch_bounds__(256) void gemm_nt128(
    const float* __restrict__ A, const float* __restrict__ B,
    const float* __restrict__ bias, float* __restrict__ C,
    int M, int N, int K)
{
  __shared__ float As[16][128];
  __shared__ float Bs[16][128];
  const int tid = threadIdx.x;
  const int tx = tid & 15, ty = tid >> 4;
  const int mbase = blockIdx.y << 7, nbase = blockIdx.x << 7;
  const int lm = tid >> 1;          // 0..127
  const int lk = (tid & 1) << 3;    // 0 or 8
  float acc[8][8];
#pragma unroll
  for (int i = 0; i < 8; i++)
#pragma unroll
    for (int j = 0; j < 8; j++) acc[i][j] = 0.f;

  for (int kk = 0; kk < K; kk += 16) {
    {
      int m = mbase + lm;
      const float* src = A + (size_t)m * K;
#pragma unroll
      for (int q = 0; q < 2; q++) {
        int kb = kk + lk + q * 4;
        float4 v = make_float4(0.f, 0.f, 0.f, 0.f);
        if (m < M) {
          if (kb + 4 <= K) {
            v = *(const float4*)(src + kb);
          } else {
            v.x = (kb + 0 < K) ? src[kb + 0] : 0.f;
            v.y = (kb + 1 < K) ? src[kb + 1] : 0.f;
            v.z = (kb + 2 < K) ? src[kb + 2] : 0.f;
            v.w = (kb + 3 < K) ? src[kb + 3] : 0.f;
          }
        }
        As[lk + q * 4 + 0][lm] = v.x;
        As[lk + q * 4 + 1][lm] = v.y;
        As[lk + q * 4 + 2][lm] = v.z;
        As[lk + q * 4 + 3][lm] = v.w;
      }
    }
    {
      int n = nbase + lm;
      const float* src = B + (size_t)n * K;
#pragma unroll
      for (int q = 0; q < 2; q++) {
        int kb = kk + lk + q * 4;
        float4 v = make_float4(0.f, 0.f, 0.f, 0.f);
        if (n < N) {
          if (kb + 4 <= K) {
            v = *(const float4*)(src + kb);
          } else {
            v.x = (kb + 0 < K) ? src[kb + 0] : 0.f;
            v.y = (kb + 1 < K) ? src[kb + 1] : 0.f;
            v.z = (kb + 2 < K) ? src[kb + 2] : 0.f;
            v.w = (kb + 3 < K) ? src[kb + 3] : 0.f;
          }
        }
        Bs[lk + q * 4 + 0][lm] = v.x;
        Bs[lk + q * 4 + 1][lm] = v.y;
        Bs[lk + q * 4 + 2][lm] = v.z;
        Bs[lk + q * 4 + 3][lm] = v.w;
      }
    }
    __syncthreads();
#pragma unroll
    for (int k = 0; k < 16; k++) {
      float4 a0 = *(const float4*)&As[k][ty * 8];
      float4 a1 = *(const float4*)&As[k][ty * 8 + 4];
      float4 b0 = *(const float4*)&Bs[k][tx * 8];
      float4 b1 = *(const float4*)&Bs[k][tx * 8 + 4];
      float av[8] = {a0.x, a0.y, a0.z, a0.w, a1.x, a1.y, a1.z, a1.w};
      float bv[8] = {b0.x, b0.y, b0.z, b0.w, b1.x, b1.y, b1.z, b1.w};
#pragma unroll
      for (int i = 0; i < 8; i++)
#pragma unroll
        for (int j = 0; j < 8; j++) acc[i][j] += av[i] * bv[j];
    }
    __syncthreads();
  }

#pragma unroll
  for (int i = 0; i < 8; i++) {
    int m = mbase + ty * 8 + i;
    if (m >= M) continue;
#pragma unroll
    for (int jq = 0; jq < 2; jq++) {
      int n = nbase + tx * 8 + jq * 4;
      if (n >= N) continue;
      float4 v = make_float4(acc[i][jq * 4], acc[i][jq * 4 + 1],
                             acc[i][jq * 4 + 2], acc[i][jq * 4 + 3]);
      if (bias) {
        v.x += bias[n]; v.y += bias[n + 1]; v.z += bias[n + 2]; v.w += bias[n + 3];
      }
      *(float4*)(C + (size_t)m * N + n) = v;
    }
  }
}

// ---------------------------------------------------------------------------
// permW: permute Wih rows to gate-interleaved order (row' = 4u+gate maps from
// row = gate*300+u) so the input-gate GEMM writes columns in the same
// interleave packB uses -> lstm elementwise reads gx as one float4 per unit.
// ---------------------------------------------------------------------------
__global__ __launch_bounds__(256) void permW_kernel(
    const float* __restrict__ W, const float* __restrict__ bias,
    float* __restrict__ Wp, float* __restrict__ bp, int K)
{
  int r = blockIdx.x;              // 0..1199 = col' = 4u+gate
  int gate = r & 3, u = r >> 2;
  int src = gate * 300 + u;
  const float* s = W + (size_t)src * K;
  float* d = Wp + (size_t)r * K;
  for (int c = threadIdx.x; c < K; c += 256) d[c] = s[c];
  if (threadIdx.x == 0) bp[r] = bias[src];
}

// ---------------------------------------------------------------------------
// packB: W (1200,300) fp32 -> MFMA B-fragment stream for 16x16x32_f16.
// Gate-interleaved column order col' = 4*u + gate  (orig n = gate*300+u).
// Item i = (nt*10+kt)*64 + lane; lane holds B[k = kt*32+(lane>>4)*8+j][col'=
// nt*16+(lane&15)] for j=0..7, f16, zero-padded for k>=300.
// ---------------------------------------------------------------------------
__global__ __launch_bounds__(256) void packB_kernel(
    const float* __restrict__ W0, const float* __restrict__ W1,
    const float* __restrict__ W2,
    uint4* __restrict__ T0, uint4* __restrict__ T1, uint4* __restrict__ T2)
{
  int i = blockIdx.x * 256 + threadIdx.x;
  if (i >= 48000) return;
  const float* W = (blockIdx.y == 0) ? W0 : (blockIdx.y == 1) ? W1 : W2;
  uint4* T = (blockIdx.y == 0) ? T0 : (blockIdx.y == 1) ? T1 : T2;
  int lane = i & 63;
  int tile = i >> 6;               // nt*10 + kt
  int nt = tile / 10, kt = tile - nt * 10;
  int lm = lane & 15, lg = lane >> 4;
  int colp = nt * 16 + lm;
  int u = colp >> 2, gate = colp & 3;
  int n = gate * 300 + u;
  U4H8 v;
#pragma unroll
  for (int j = 0; j < 8; j++) {
    int k = kt * 32 + lg * 8 + j;
    float x = (k < 300) ? W[(size_t)n * 300 + k] : 0.f;
    v.e[j] = (_Float16)x;
  }
  T[i] = v.u;
}

// ---------------------------------------------------------------------------
// Persistent LSTM via MFMA (16x16x32 f16): R=8 rows/block, all 64 steps.
// 1024 threads = 16 waves (4 waves/SIMD -> VGPR capped at 128); wave w owns
// N-tiles nt = w, w+16, ... (<75): 5 tiles for w<11 else 4.
// XCD-partitioned: xcd = b&7, dir = xcd>>2, rowgroup = (b>>3)*4 + (xcd&3).
// h in LDS as A-fragment layout [16][328] f16 (rows 8-15 & k>=300 zero).
// Gates staged gsh[m][1204] f32 (cols interleaved 4u+gate): elementwise reads
// are sequential ds_read_b128 (conflict-free); D-writes hit all 32 banks
// (4*1204 = 16 mod 32). gx is gate-interleaved (permW) -> one float4/unit.
// Per-tile MFMA split into two 5-deep acc chains; B prefetched half-tile
// ahead (bA[5]/bB[5]) to stay under the 128-VGPR / 4-wave-per-SIMD cliff.
// LDS = 10.25 KB + 37.6 KB = 47.9 KB.
// ---------------------------------------------------------------------------
__global__ __launch_bounds__(1024, 1) void lstm_mfma(
    const uint4* __restrict__ WB0, const uint4* __restrict__ WB1, // packed B-frags
    const float* __restrict__ gx0, const float* __restrict__ gx1, // (64,NB,1200) interleaved
    float* __restrict__ hist0, float* __restrict__ hist1,         // (64,NB,300) or null
    float* __restrict__ hfin,                                     // (2,NB,300) or null
    int NB)
{
  const int b = blockIdx.x;
  const int xcd = b & 7;
  const int grp = b >> 3;
  const int dirb = xcd >> 2;
  const int n0 = (grp * 4 + (xcd & 3)) * 8;
  const int tid = threadIdx.x;
  const int wv = tid >> 6, lane = tid & 63;
  const int lm = lane & 15, lg = lane >> 4;

  const uint4* WB = dirb ? WB1 : WB0;
  const float* gx = dirb ? gx1 : gx0;
  float* hist = dirb ? hist1 : hist0;

  __shared__ _Float16 hA[16 * 328];         // [m][k], pitch 328
  __shared__ __align__(16) float gsh[8 * 1204];  // [m][col'(4u+gate)], pitch 1204

  for (int e = tid; e < 16 * 328; e += 1024) hA[e] = (_Float16)0.f;

  // t-invariant elementwise indices: e = tid + q*1024 -> (m,u)
  int mq[3], uq[3], gxoff[3], hoff[3];
  bool act[3];
#pragma unroll
  for (int q = 0; q < 3; q++) {
    int e = tid + q * 1024;
    act[q] = (e < 2400);
    int m = e / 300;
    int u = e - m * 300;
    if (!act[q]) { m = 0; u = 0; }
    mq[q] = m; uq[q] = u;
    gxoff[q] = (n0 + m) * 1200 + 4 * u;
    hoff[q] = (n0 + m) * 300 + u;
  }

  const int nnt = (wv < 11) ? 5 : 4;        // 75 N-tiles over 16 waves
  float crs[3] = {0.f, 0.f, 0.f};
  __syncthreads();

  for (int t = 0; t < 64; t++) {
    const int tg = dirb ? (63 - t) : t;
    const size_t gxstep = (size_t)tg * NB * 1200;
    const size_t hstep = (size_t)tg * NB * 300;

    // prefetch x-gates (interleaved i,f,g,o) — consumed post-barrier
    float4 gxv[3];
#pragma unroll
    for (int q = 0; q < 3; q++) {
      gxv[q] = make_float4(0.f, 0.f, 0.f, 0.f);
      if (act[q]) gxv[q] = *(const float4*)(gx + gxstep + gxoff[q]);
    }

    // A-fragment cache: a[kt] = hA[m=lm][kt*32 + lg*8 .. +7]
    U4H8 afrag[10];
#pragma unroll
    for (int kt = 0; kt < 10; kt++)
      afrag[kt].u = *(const uint4*)&hA[lm * 328 + kt * 32 + lg * 8];

    // MFMA over this wave's N-tiles, half-tile-ahead B prefetch
    uint4 bA[5], bB[5];
#pragma unroll
    for (int kt = 0; kt < 5; kt++)
      bA[kt] = WB[(size_t)(wv * 10 + kt) * 64 + lane];

    for (int i = 0; i < nnt; i++) {
      int nt = wv + 16 * i;
      // load second half of this tile
#pragma unroll
      for (int kt = 0; kt < 5; kt++)
        bB[kt] = WB[(size_t)((nt * 10 + 5 + kt) * 64 + lane)];
      f32x4v acc0 = {0.f, 0.f, 0.f, 0.f};
#pragma unroll
      for (int kt = 0; kt < 5; kt++) {
        U4H8 bb; bb.u = bA[kt];
        acc0 = __builtin_amdgcn_mfma_f32_16x16x32_f16(afrag[kt].h, bb.h, acc0, 0, 0, 0);
      }
      // load first half of next tile
      if (i + 1 < nnt) {
        int ntn = nt + 16;
#pragma unroll
        for (int kt = 0; kt < 5; kt++)
          bA[kt] = WB[(size_t)(ntn * 10 + kt) * 64 + lane];
      }
      f32x4v acc1 = {0.f, 0.f, 0.f, 0.f};
#pragma unroll
      for (int kt = 0; kt < 5; kt++) {
        U4H8 bb; bb.u = bB[kt];
        acc1 = __builtin_amdgcn_mfma_f32_16x16x32_f16(afrag[5 + kt].h, bb.h, acc1, 0, 0, 0);
      }
      // D: col'=nt*16+lm, m=lg*4+r; keep m<8 (rows 8-15 are zero-padding)
      if (lg < 2) {
#pragma unroll
        for (int r = 0; r < 4; r++)
          gsh[(lg * 4 + r) * 1204 + nt * 16 + lm] = acc0[r] + acc1[r];
      }
    }
    __syncthreads();

    // elementwise: one unit per (thread,q); gates contiguous in gsh & gx
#pragma unroll
    for (int q = 0; q < 3; q++) {
      if (act[q]) {
        const float4 gs = *(const float4*)&gsh[mq[q] * 1204 + 4 * uq[q]];
        float gi = gxv[q].x + gs.x;
        float gf = gxv[q].y + gs.y;
        float gg = gxv[q].z + gs.z;
        float go = gxv[q].w + gs.w;
        float si = fsig(gi);
        float sf = fsig(gf);
        float so = fsig(go);
        float cc = sf * crs[q] + si * ftanh(gg);
        float h = so * ftanh(cc);
        crs[q] = cc;
        hA[mq[q] * 328 + uq[q]] = (_Float16)h;
        if (hist) hist[hstep + hoff[q]] = h;
        if (hfin && t == 63) hfin[(size_t)dirb * NB * 300 + hoff[q]] = h;
      }
    }
    __syncthreads();
  }
}

// ---------------------------------------------------------------------------
__global__ void embed_kernel(
    const int* __restrict__ prem, const int* __restrict__ hyp,
    const float* __restrict__ embW, float* __restrict__ comb)
{
  size_t i = (size_t)blockIdx.x * 256 + threadIdx.x;
  if (i >= (size_t)64 * 256 * 75) return;
  int d4 = (int)(i % 75);
  size_t r = i / 75;
  int n = (int)(r % 256);
  int t = (int)(r / 256);
  int id = (n < 128) ? prem[t * 128 + n] : hyp[t * 128 + (n - 128)];
  float4 v = *(const float4*)(embW + (size_t)id * 300 + d4 * 4);
  *(float4*)(comb + ((size_t)t * 256 + n) * 300 + d4 * 4) = v;
}

// ---------------------------------------------------------------------------
// norm4: weighted norms for all four W sets per (dir,t,n,l) + plain row norms.
// ---------------------------------------------------------------------------
__global__ __launch_bounds__(320) void norm4_kernel(
    const float* __restrict__ hs_fw, const float* __restrict__ hs_bw,
    const float* __restrict__ mp_W,
    float* __restrict__ nm4, float* __restrict__ pnorm)
{
  const int t = blockIdx.x, n = blockIdx.y, dir = blockIdx.z;
  const float* HS = dir ? hs_bw : hs_fw;
  const float* row = HS + ((size_t)t * 256 + n) * 300;
  __shared__ float sh[300];
  const int tid = threadIdx.x, g = tid >> 4, lane = tid & 15;
  for (int k = tid; k < 300; k += 320) sh[k] = row[k];
  __syncthreads();
  if (g == 0) {
    float s2 = 0.f;
    for (int k = lane; k < 300; k += 16) { float x = sh[k]; s2 += x * x; }
    for (int o = 8; o; o >>= 1) s2 += __shfl_down(s2, o, 16);
    if (lane == 0) pnorm[((size_t)dir * 64 + t) * 256 + n] = sqrtf(s2);
  }
#pragma unroll
  for (int wset = 0; wset < 4; wset++) {
    const float* W = mp_W + dir * 24000 + wset * 6000 + g * 300;
    float s1 = 0.f;
    for (int k = lane; k < 300; k += 16) {
      float x = sh[k];
      float w = W[k];
      s1 += x * x * w * w;
    }
    for (int o = 8; o; o >>= 1) s1 += __shfl_down(s1, o, 16);
    if (lane == 0)
      nm4[((((size_t)dir * 4 + wset) * 64 + t) * 256 + n) * 20 + g] = sqrtf(s1);
  }
}

// ---------------------------------------------------------------------------
// att: per (b,z), att[64,64] cosine GEMM -> normalized w (watt) + argmax idx.
// ---------------------------------------------------------------------------
__global__ __launch_bounds__(256) void att_kernel(
    const float* __restrict__ hs_fw, const float* __restrict__ hs_bw,
    const float* __restrict__ pnorm,
    float* __restrict__ watt, int* __restrict__ idxbuf)
{
  const int b = blockIdx.x, z = blockIdx.y;
  const int dir = z & 1;
  const float* HS = dir ? hs_bw : hs_fw;
  const int p_n = (z < 2) ? b : 128 + b;
  const int h_n = (z < 2) ? 128 + b : b;
  const float* pnD = pnorm + (size_t)dir * 16384;

  __shared__ float pch[64 * 100];
  __shared__ float hch[64 * 100];
  __shared__ float att[64 * 65];
  __shared__ float winv_sh[64];

  const int tid = threadIdx.x;
  const int i = tid >> 4, j = tid & 15;
  float acc[4][4];
#pragma unroll
  for (int a = 0; a < 4; a++)
#pragma unroll
    for (int c = 0; c < 4; c++) acc[a][c] = 0.f;

  for (int kc = 0; kc < 300; kc += 100) {
    for (int e = tid; e < 1600; e += 256) {
      int row = e / 25, kq = e - row * 25;
      float4 v = *(const float4*)(HS + ((size_t)row * 256 + p_n) * 300 + kc + kq * 4);
      *(float4*)&pch[row * 100 + kq * 4] = v;
      float4 w = *(const float4*)(HS + ((size_t)row * 256 + h_n) * 300 + kc + kq * 4);
      *(float4*)&hch[row * 100 + kq * 4] = w;
    }
    __syncthreads();
#pragma unroll 5
    for (int kq = 0; kq < 25; kq++) {
      float4 av[4], bv[4];
#pragma unroll
      for (int a = 0; a < 4; a++) av[a] = *(const float4*)&pch[(i + 16 * a) * 100 + kq * 4];
#pragma unroll
      for (int c = 0; c < 4; c++) bv[c] = *(const float4*)&hch[(j + 16 * c) * 100 + kq * 4];
#pragma unroll
      for (int a = 0; a < 4; a++)
#pragma unroll
        for (int c = 0; c < 4; c++)
          acc[a][c] += av[a].x * bv[c].x + av[a].y * bv[c].y + av[a].z * bv[c].z + av[a].w * bv[c].w;
    }
    __syncthreads();
  }

#pragma unroll
  for (int a = 0; a < 4; a++) {
    int t = i + 16 * a;
    float pn = pnD[t * 256 + p_n] + EPSF;
#pragma unroll
    for (int c = 0; c < 4; c++) {
      int s = j + 16 * c;
      float hn = pnD[s * 256 + h_n] + EPSF;
      att[t * 65 + s] = acc[a][c] / (pn * hn);
    }
  }
  __syncthreads();
  if (tid < 64) {
    int t = tid;
    float ssum = 0.f, mx = -1e30f; int mi = 0;
    for (int s = 0; s < 64; s++) {
      float a = att[t * 65 + s];
      ssum += a;
      if (a > mx) { mx = a; mi = s; }
    }
    winv_sh[t] = 1.f / (ssum + EPSF);
    idxbuf[((size_t)z * 128 + b) * 64 + t] = mi;
  }
  __syncthreads();
  for (int e = tid; e < 4096; e += 256) {
    int t = e >> 6, s = e & 63;
    watt[((size_t)z * 128 + b) * 4096 + t * 64 + s] = att[t * 65 + s] * winv_sh[t];
  }
}

// ---------------------------------------------------------------------------
// hmean: per (b,z): hmean[t,k] = sum_s w[t,s]*h[s,k]
// ---------------------------------------------------------------------------
__global__ __launch_bounds__(256) void hmean_kernel(
    const float* __restrict__ hs_fw, const float* __restrict__ hs_bw,
    const float* __restrict__ watt, float* __restrict__ hmeanbuf)
{
  const int b = blockIdx.x, z = blockIdx.y;
  const int dir = z & 1;
  const float* HS = dir ? hs_bw : hs_fw;
  const int h_n = (z < 2) ? 128 + b : b;

  __shared__ float wsh[64 * 65];
  __shared__ float hch[64 * 128];

  const int tid = threadIdx.x;
  const int ti = tid >> 4, kj = tid & 15;
  const float* wsrc = watt + ((size_t)z * 128 + b) * 4096;
  for (int e = tid; e < 4096; e += 256) {
    int t = e >> 6, s = e & 63;
    wsh[t * 65 + s] = wsrc[t * 64 + s];
  }

  for (int kbase = 0; kbase < 300; kbase += 128) {
    int kw = min(128, 300 - kbase);
    int nf4 = kw >> 2;  // 32,32,11
    __syncthreads();
    for (int e = tid; e < 64 * nf4; e += 256) {
      int row = e / nf4, q = e - row * nf4;
      float4 v = *(const float4*)(HS + ((size_t)row * 256 + h_n) * 300 + kbase + q * 4);
      *(float4*)&hch[row * 128 + q * 4] = v;
    }
    __syncthreads();
    float acc[4][8];
#pragma unroll
    for (int a = 0; a < 4; a++)
#pragma unroll
      for (int c = 0; c < 8; c++) acc[a][c] = 0.f;
    for (int s = 0; s < 64; s++) {
      float4 h0 = *(const float4*)&hch[s * 128 + 4 * kj];
      float4 h1 = *(const float4*)&hch[s * 128 + 4 * (kj + 16)];
#pragma unroll
      for (int a = 0; a < 4; a++) {
        float w = wsh[(4 * ti + a) * 65 + s];
        acc[a][0] += w * h0.x; acc[a][1] += w * h0.y; acc[a][2] += w * h0.z; acc[a][3] += w * h0.w;
        acc[a][4] += w * h1.x; acc[a][5] += w * h1.y; acc[a][6] += w * h1.z; acc[a][7] += w * h1.w;
      }
    }
#pragma unroll
    for (int a = 0; a < 4; a++) {
      int t = 4 * ti + a;
#pragma unroll
      for (int c = 0; c < 2; c++) {
        int kq = kj + 16 * c;
        if (kq * 4 < kw) {
          int k = kbase + kq * 4;
          float4 v = make_float4(acc[a][4 * c], acc[a][4 * c + 1], acc[a][4 * c + 2], acc[a][4 * c + 3]);
          *(float4*)&hmeanbuf[(((size_t)z * 128 + b) * 64 + t) * 300 + k] = v;
        }
      }
    }
  }
}

// ---------------------------------------------------------------------------
// maxp: per (b,z,tt): num[t,s,l] GEMM with register tiles, fused max over s.
// ---------------------------------------------------------------------------
__global__ __launch_bounds__(128) void maxp_kernel(
    const float* __restrict__ hs_fw, const float* __restrict__ hs_bw,
    const float* __restrict__ mp_W, const float* __restrict__ nm4,
    float* __restrict__ m_out)
{
  const int b = blockIdx.x, z = blockIdx.y, tt = blockIdx.z;
  const int dir = z & 1;
  const float* HS = dir ? hs_bw : hs_fw;
  const int p_n = (z < 2) ? b : 128 + b;
  const int h_n = (z < 2) ? 128 + b : b;
  const int t_base = tt * 8;
  const float* Wm = mp_W + dir * 24000 + 6000;

  __shared__ float psh[8 * 100];
  __shared__ float hsh[64 * 100];
  __shared__ float wsh[20 * 100];

  const int tid = threadIdx.x;
  const int t_loc = tid >> 4;
  const int sg = (tid >> 1) & 7;
  const int lg = tid & 1;
  const int t = t_base + t_loc;

  float acc[8][10];
#pragma unroll
  for (int i = 0; i < 8; i++)
#pragma unroll
    for (int j = 0; j < 10; j++) acc[i][j] = 0.f;

  for (int kc = 0; kc < 300; kc += 100) {
    for (int e = tid; e < 200; e += 128) {
      int row = e / 25, q = e - row * 25;
      float4 v = *(const float4*)(HS + ((size_t)(t_base + row) * 256 + p_n) * 300 + kc + q * 4);
      *(float4*)&psh[row * 100 + q * 4] = v;
    }
    for (int e = tid; e < 1600; e += 128) {
      int row = e / 25, q = e - row * 25;
      float4 v = *(const float4*)(HS + ((size_t)row * 256 + h_n) * 300 + kc + q * 4);
      *(float4*)&hsh[row * 100 + q * 4] = v;
    }
    for (int e = tid; e < 500; e += 128) {
      int row = e / 25, q = e - row * 25;
      float4 w = *(const float4*)(Wm + (size_t)row * 300 + kc + q * 4);
      w.x *= w.x; w.y *= w.y; w.z *= w.z; w.w *= w.w;
      *(float4*)&wsh[row * 100 + q * 4] = w;
    }
    __syncthreads();
    for (int kq = 0; kq < 25; kq++) {
      float4 pv = *(const float4*)&psh[t_loc * 100 + kq * 4];
      float4 hv[8];
#pragma unroll
      for (int i = 0; i < 8; i++) hv[i] = *(const float4*)&hsh[(sg + 8 * i) * 100 + kq * 4];
#pragma unroll
      for (int j = 0; j < 10; j++) {
        float4 wv = *(const float4*)&wsh[(lg * 10 + j) * 100 + kq * 4];
        float pwx = pv.x * wv.x, pwy = pv.y * wv.y, pwz = pv.z * wv.z, pww = pv.w * wv.w;
#pragma unroll
        for (int i = 0; i < 8; i++)
          acc[i][j] += hv[i].x * pwx + hv[i].y * pwy + hv[i].z * pwz + hv[i].w * pww;
      }
    }
    __syncthreads();
  }

  const float* nmD = nm4 + ((size_t)dir * 4 + 1) * 327680;
  float pn[10], rmax[10];
#pragma unroll
  for (int j = 0; j < 10; j++) {
    pn[j] = nmD[((size_t)t * 256 + p_n) * 20 + lg * 10 + j];
    rmax[j] = -1e30f;
  }
#pragma unroll
  for (int i = 0; i < 8; i++) {
    int s = sg + 8 * i;
#pragma unroll
    for (int j = 0; j < 10; j++) {
      float hn = nmD[((size_t)s * 256 + h_n) * 20 + lg * 10 + j];
      float r = acc[i][j] / (pn[j] * hn + EPSF);
      rmax[j] = fmaxf(rmax[j], r);
    }
  }
#pragma unroll
  for (int off = 8; off >= 2; off >>= 1)
#pragma unroll
    for (int j = 0; j < 10; j++)
      rmax[j] = fmaxf(rmax[j], __shfl_down(rmax[j], off));
  if (sg == 0) {
    float* mrow = m_out + ((size_t)t * 128 + b) * 320 + z * 80;
#pragma unroll
    for (int j = 0; j < 10; j++) mrow[20 + lg * 10 + j] = rmax[j];
  }
}

// ---------------------------------------------------------------------------
// rest: per (b,z): full / attm / maxattm for all t. W^2 staged once in LDS.
// ---------------------------------------------------------------------------
__global__ __launch_bounds__(320) void rest_kernel(
    const float* __restrict__ hs_fw, const float* __restrict__ hs_bw,
    const float* __restrict__ mp_W, const float* __restrict__ nm4,
    const float* __restrict__ hmeanbuf, const int* __restrict__ idxbuf,
    float* __restrict__ m_out)
{
  const int b = blockIdx.x, z = blockIdx.y;
  const int dir = z & 1;
  const float* HS = dir ? hs_bw : hs_fw;
  const int p_n = (z < 2) ? b : 128 + b;
  const int h_n = (z < 2) ? 128 + b : b;
  const int v_t = dir ? 0 : 63;

  __shared__ float w2f[6000], w2a[6000], w2m[6000];
  __shared__ float vsh[300], psh[300], hmsh[300], hxsh[300];

  const int tid = threadIdx.x;
  const int g = tid >> 4, lane = tid & 15;
  const float* Wf = mp_W + dir * 24000;
  const float* Wa = Wf + 12000;
  const float* Wma = Wf + 18000;
  for (int e = tid; e < 6000; e += 320) {
    float a = Wf[e], bb = Wa[e], c = Wma[e];
    w2f[e] = a * a; w2a[e] = bb * bb; w2m[e] = c * c;
  }
  for (int e = tid; e < 300; e += 320)
    vsh[e] = HS[((size_t)v_t * 256 + h_n) * 300 + e];
  __syncthreads();

  const float* base0 = nm4 + ((size_t)dir * 4 + 0) * 327680;
  const float* base2 = nm4 + ((size_t)dir * 4 + 2) * 327680;
  const float* base3 = nm4 + ((size_t)dir * 4 + 3) * 327680;
  const float vnf = base0[((size_t)v_t * 256 + h_n) * 20 + g];

  for (int t = 0; t < 64; t++) {
    int idx = idxbuf[((size_t)z * 128 + b) * 64 + t];
    __syncthreads();
    for (int e = tid; e < 300; e += 320) {
      psh[e] = HS[((size_t)t * 256 + p_n) * 300 + e];
      hmsh[e] = hmeanbuf[(((size_t)z * 128 + b) * 64 + t) * 300 + e];
      hxsh[e] = HS[((size_t)idx * 256 + h_n) * 300 + e];
    }
    __syncthreads();
    float nf = 0.f, na = 0.f, qa = 0.f, nm = 0.f;
#pragma unroll
    for (int c = 0; c < 5; c++) {
      int k4 = lane + 16 * c;
      if (k4 < 75) {
        float4 p = *(const float4*)&psh[4 * k4];
        float4 v = *(const float4*)&vsh[4 * k4];
        float4 hm = *(const float4*)&hmsh[4 * k4];
        float4 hx = *(const float4*)&hxsh[4 * k4];
        float4 wf = *(const float4*)&w2f[g * 300 + 4 * k4];
        float4 wa = *(const float4*)&w2a[g * 300 + 4 * k4];
        float4 wm = *(const float4*)&w2m[g * 300 + 4 * k4];
        nf += p.x * v.x * wf.x + p.y * v.y * wf.y + p.z * v.z * wf.z + p.w * v.w * wf.w;
        na += p.x * hm.x * wa.x + p.y * hm.y * wa.y + p.z * hm.z * wa.z + p.w * hm.w * wa.w;
        qa += hm.x * hm.x * wa.x + hm.y * hm.y * wa.y + hm.z * hm.z * wa.z + hm.w * hm.w * wa.w;
        nm += p.x * hx.x * wm.x + p.y * hx.y * wm.y + p.z * hx.z * wm.z + p.w * hx.w * wm.w;
      }
    }
#pragma unroll
    for (int o = 8; o; o >>= 1) {
      nf += __shfl_down(nf, o);
      na += __shfl_down(na, o);
      qa += __shfl_down(qa, o);
      nm += __shfl_down(nm, o);
    }
    if (lane == 0) {
      float pnf = base0[((size_t)t * 256 + p_n) * 20 + g];
      float pna = base2[((size_t)t * 256 + p_n) * 20 + g];
      float pnm = base3[((size_t)t * 256 + p_n) * 20 + g];
      float qnm = base3[((size_t)idx * 256 + h_n) * 20 + g];
      float* mrow = m_out + ((size_t)t * 128 + b) * 320 + z * 80;
      mrow[g] = nf / (pnf * vnf + EPSF);
      mrow[40 + g] = na / (pna * sqrtf(qa) + EPSF);
      mrow[60 + g] = nm / (pnm * qnm + EPSF);
    }
  }
}

// ---------------------------------------------------------------------------
__global__ __launch_bounds__(256) void mlp_kernel(
    const float* __restrict__ shA0, const float* __restrict__ shA1,
    const float* __restrict__ bnG, const float* __restrict__ bnB,
    const float* __restrict__ W1, const float* __restrict__ b1,
    const float* __restrict__ W2, const float* __restrict__ b2,
    const float* __restrict__ outW, const float* __restrict__ outb,
    float* __restrict__ out)
{
  const int b = blockIdx.x;
  const int tid = threadIdx.x;
  __shared__ float x0[600], x1[600];
  const float inv = 1.0f / sqrtf(1.0f + 1e-5f);
  for (int j = tid; j < 600; j += 256) {
    float v = (j < 300) ? shA0[b * 300 + j] : shA1[b * 300 + (j - 300)];
    x0[j] = bnG[j] * v * inv + bnB[j];
  }
  __syncthreads();
  for (int j = tid; j < 600; j += 256) {
    float acc = b1[j];
    const float* w = W1 + (size_t)j * 600;
    for (int k = 0; k < 600; k++) acc += x0[k] * w[k];
    float r = fmaxf(acc, 0.f);
    x1[j] = bnG[600 + j] * r * inv + bnB[600 + j];
  }
  __syncthreads();
  for (int j = tid; j < 600; j += 256) {
    float acc = b2[j];
    const float* w = W2 + (size_t)j * 600;
    for (int k = 0; k < 600; k++) acc += x1[k] * w[k];
    float r = fmaxf(acc, 0.f);
    x0[j] = bnG[1200 + j] * r * inv + bnB[1200 + j];
  }
  __syncthreads();
  if (tid < 3) {
    float acc = outb[tid];
    const float* w = outW + tid * 600;
    for (int k = 0; k < 600; k++) acc += x0[k] * w[k];
    out[b * 3 + tid] = acc;
  }
}

// ---------------------------------------------------------------------------
extern "C" void kernel_launch(void* const* d_in, const int* in_sizes, int n_in,
                              void* d_out, int out_size, void* d_ws, size_t ws_size,
                              hipStream_t stream) {
  const int* premise = (const int*)d_in[0];
  const int* hypothesis = (const int*)d_in[1];
  const float* embW = (const float*)d_in[2];
  const float* cWih = (const float*)d_in[3];
  const float* cWhh = (const float*)d_in[4];
  const float* cb = (const float*)d_in[5];
  const float* mpW = (const float*)d_in[6];
  const float* aWihF = (const float*)d_in[7];
  const float* aWhhF = (const float*)d_in[8];
  const float* abF = (const float*)d_in[9];
  const float* aWihB = (const float*)d_in[10];
  const float* aWhhB = (const float*)d_in[11];
  const float* abB = (const float*)d_in[12];
  const float* bnG = (const float*)d_in[13];
  const float* bnB = (const float*)d_in[14];
  const float* W1 = (const float*)d_in[15];
  const float* b1 = (const float*)d_in[16];
  const float* W2 = (const float*)d_in[17];
  const float* b2 = (const float*)d_in[18];
  const float* outW = (const float*)d_in[19];
  const float* outb = (const float*)d_in[20];
  float* out = (float*)d_out;

  float* ws = (float*)d_ws;
  // workspace layout (floats)
  float* comb  = ws + 0;           // 4,915,200  (T,256,300); WB packs + aWih perms overlay after ctx-gates GEMM
  float* gates = ws + 4915200;     // 19,660,800 (T,256,1200); overlaid after ctx LSTM
  float* hsfw  = ws + 24576000;    // 4,915,200  (cWih perm overlays here pre-LSTM)
  float* hsbw  = ws + 29491200;    // 4,915,200
  float* pnorm = ws + 34406400;    // 32,768    [2][64][256]
  float* mbuf  = ws + 35094528;    // 2,621,440 (T,128,320)
  float* sha   = ws + 38023168;    // 76,800    agg final h [2][128][300]

  // packed MFMA B-fragment weights overlay in comb region (dead after ctx-gates GEMM)
  // each: 48,000 uint4 = 192,000 float-slots
  uint4* WBctx = (uint4*)comb;
  uint4* WBaf  = (uint4*)(comb + 192000);
  uint4* WBab  = (uint4*)(comb + 384000);
  // gate-interleaved agg input weights (dead comb region, after WB packs)
  float* aWihFP = comb + 576000;   // 384,000
  float* aWihBP = comb + 960000;   // 384,000
  float* abFP   = comb + 1344000;  // 1,200
  float* abBP   = comb + 1345200;  // 1,200

  // gate-interleaved ctx input weights: hsfw region is dead until ctx LSTM
  float* cWihP = hsfw;             // 360,000
  float* cbP   = hsfw + 360000;    // 1,200

  // overlays inside the dead ctx-gates region (valid between ctx LSTM and agg GEMMs)
  float* watt     = gates;                 // 2,097,152 [4][128][64][64]
  float* hmeanbuf = gates + 2097152;       // 9,830,400 [4][128][64][300]
  int*   idxbuf   = (int*)(gates + 11927552); // 32,768 [4][128][64]
  float* nm4      = gates + 11960320;      // 2,621,440 [2][4][64][256][20]

  // 1) embed + ctx input-weight gate-interleave
  embed_kernel<<<dim3(4800), dim3(256), 0, stream>>>(premise, hypothesis, embW, comb);
  permW_kernel<<<dim3(1200), dim3(256), 0, stream>>>(cWih, cb, cWihP, cbP, 300);

  // 2) ctx input gates (consumes comb) — fp32, gate-interleaved columns
  gemm_nt128<<<dim3(10, 128), dim3(256), 0, stream>>>(comb, cWihP, cbP, gates, 16384, 1200, 300);

  // 3) pack recurrent weights into MFMA B-fragment stream (dead comb region)
  //    + gate-interleave the agg input weights
  packB_kernel<<<dim3(188, 3), dim3(256), 0, stream>>>(
      cWhh, aWhhF, aWhhB, WBctx, WBaf, WBab);
  permW_kernel<<<dim3(1200), dim3(256), 0, stream>>>(aWihF, abF, aWihFP, abFP, 320);
  permW_kernel<<<dim3(1200), dim3(256), 0, stream>>>(aWihB, abB, aWihBP, abBP, 320);

  // 4) context LSTM: MFMA, R=8, 64 blocks (32/dir), 16 waves/block
  lstm_mfma<<<dim3(64), dim3(1024), 0, stream>>>(
      WBctx, WBctx, gates, gates, hsfw, hsbw, nullptr, 256);

  // 5) norms (all 4 W sets) + plain norms
  norm4_kernel<<<dim3(64, 256, 2), dim3(320), 0, stream>>>(hsfw, hsbw, mpW, nm4, pnorm);

  // 6) matching pipeline
  att_kernel<<<dim3(128, 4), dim3(256), 0, stream>>>(hsfw, hsbw, pnorm, watt, idxbuf);
  hmean_kernel<<<dim3(128, 4), dim3(256), 0, stream>>>(hsfw, hsbw, watt, hmeanbuf);
  maxp_kernel<<<dim3(128, 4, 8), dim3(128), 0, stream>>>(hsfw, hsbw, mpW, nm4, mbuf);
  rest_kernel<<<dim3(128, 4), dim3(320), 0, stream>>>(hsfw, hsbw, mpW, nm4, hmeanbuf, idxbuf, mbuf);

  // 7) agg input gates — fp32, gate-interleaved columns
  float* gaf = gates;
  float* gab = gates + 9830400;
  gemm_nt128<<<dim3(10, 64), dim3(256), 0, stream>>>(mbuf, aWihFP, abFP, gaf, 8192, 1200, 320);
  gemm_nt128<<<dim3(10, 64), dim3(256), 0, stream>>>(mbuf, aWihBP, abBP, gab, 8192, 1200, 320);

  // 8) aggregation LSTM: MFMA, R=8, 32 blocks (16/dir), 16 waves/block
  lstm_mfma<<<dim3(32), dim3(1024), 0, stream>>>(
      WBaf, WBab, gaf, gab, nullptr, nullptr, sha, 128);

  // 9) MLP head
  mlp_kernel<<<dim3(128), dim3(256), 0, stream>>>(
      sha, sha + 38400, bnG, bnB, W1, b1, W2, b2, outW, outb, out);
}